// Round 2
// baseline (504.108 us; speedup 1.0000x reference)
//
#include <hip/hip_runtime.h>
#include <hip/hip_bf16.h>

#define HH   64
#define H2   128
#define VOC  64
#define LSEQ 2048

typedef float f16v __attribute__((ext_vector_type(16)));

// ---------------------------------------------------------------------------
// Kernel 1: collapse embed -> FFN -> LN -> {kn, v, q} projections into
// per-token tables (VOCAB=64 entries of H=64 floats each).
// ---------------------------------------------------------------------------
__global__ __launch_bounds__(128) void build_tables(
    const float* __restrict__ embed, const float* __restrict__ w1, const float* __restrict__ b1,
    const float* __restrict__ w2, const float* __restrict__ b2,
    const float* __restrict__ ln_g, const float* __restrict__ ln_b,
    const float* __restrict__ wk, const float* __restrict__ wv, const float* __restrict__ wq,
    float* __restrict__ kn_t, float* __restrict__ v_t, float* __restrict__ q_t)
{
    const int tok = blockIdx.x;
    const int tid = threadIdx.x;
    __shared__ float e_lds[HH];
    __shared__ float h_lds[H2];
    __shared__ float hs_lds[HH];

    if (tid < HH) e_lds[tid] = embed[tok * HH + tid];
    __syncthreads();

    // hidden = relu(e @ w1 + b1), one thread per hidden unit (128)
    {
        float s = b1[tid];
        #pragma unroll 8
        for (int i = 0; i < HH; ++i) s = fmaf(e_lds[i], w1[i * H2 + tid], s);
        h_lds[tid] = fmaxf(s, 0.f);
    }
    __syncthreads();

    // x = e + hidden @ w2 + b2 ; hs = layernorm(x)*g+b   (threads 0..63 = wave 0)
    if (tid < HH) {
        float f = b2[tid];
        #pragma unroll 8
        for (int j = 0; j < H2; ++j) f = fmaf(h_lds[j], w2[j * HH + tid], f);
        float x = e_lds[tid] + f;
        float sum = x, sq = x * x;
        #pragma unroll
        for (int m = 1; m < 64; m <<= 1) { sum += __shfl_xor(sum, m); sq += __shfl_xor(sq, m); }
        float mu  = sum * (1.f / HH);
        float var = sq * (1.f / HH) - mu * mu;
        hs_lds[tid] = (x - mu) * rsqrtf(var + 1e-5f) * ln_g[tid] + ln_b[tid];
    }
    __syncthreads();

    if (tid < HH) {
        float k = 0.f, v = 0.f, q = 0.f;
        #pragma unroll 8
        for (int j = 0; j < HH; ++j) {
            float h = hs_lds[j];
            k = fmaf(h, wk[j * HH + tid], k);
            v = fmaf(h, wv[j * HH + tid], v);
            q = fmaf(h, wq[j * HH + tid], q);
        }
        float kk = k * k;
        #pragma unroll
        for (int m = 1; m < 64; m <<= 1) kk += __shfl_xor(kk, m);
        float kn = k / fmaxf(sqrtf(kk), 1e-12f);
        kn_t[tok * HH + tid] = kn;
        v_t [tok * HH + tid] = v;
        q_t [tok * HH + tid] = q;
    }
}

// ---------------------------------------------------------------------------
// Kernel 2: per-batch sequential delta-rule scan + fused output head.
// One block (256 threads, 4 waves) per batch. Thread (i = tid>>2, jg = tid&3)
// owns M[i][jg*16 .. jg*16+15] in registers. No __syncthreads in the scan
// loop: the quad-reduce is intra-wave (__shfl_xor 1,2 -> DPP quad_perm).
// Tokens prefetched 2 ahead, k/v vectors 1 ahead.
// ---------------------------------------------------------------------------
__global__ __launch_bounds__(256) void delta_scan(
    const int* __restrict__ seq,
    const float* __restrict__ kn_t, const float* __restrict__ v_t, const float* __restrict__ q_t,
    const float* __restrict__ wrp, const float* __restrict__ brp,
    const float* __restrict__ wout, const float* __restrict__ bout,
    float* __restrict__ out)
{
    __shared__ __align__(64) float kn_lds[VOC * HH];
    __shared__ __align__(64) float v_lds[VOC * HH];
    __shared__ __align__(16) int   seq_lds[LSEQ + 4];
    __shared__ float r_lds[HH];
    __shared__ float t_lds[HH];

    const int b   = blockIdx.x;
    const int tid = threadIdx.x;

    // cooperative staging: tables (2 x 16KB) + token row (8KB)
    {
        const float4* s1 = (const float4*)kn_t; float4* d1 = (float4*)kn_lds;
        const float4* s2 = (const float4*)v_t;  float4* d2 = (float4*)v_lds;
        #pragma unroll
        for (int r = 0; r < 4; ++r) {
            d1[tid + 256 * r] = s1[tid + 256 * r];
            d2[tid + 256 * r] = s2[tid + 256 * r];
        }
        const int4* s3 = (const int4*)(seq + (long)b * LSEQ);
        int4* d3 = (int4*)seq_lds;
        #pragma unroll
        for (int r = 0; r < 2; ++r) d3[tid + 256 * r] = s3[tid + 256 * r];
        if (tid == 0) { seq_lds[LSEQ] = 0; seq_lds[LSEQ + 1] = 0; }
    }
    __syncthreads();

    const int i  = tid >> 2;          // M row this thread contributes to
    const int j0 = (tid & 3) * 16;    // column slice base

    float M[16];
    #pragma unroll
    for (int jj = 0; jj < 16; ++jj) M[jj] = 0.f;

    int  tok  = seq_lds[0];
    f16v K    = *(const f16v*)&kn_lds[tok * HH + j0];
    float vi  = v_lds[tok * HH + i];
    int  tokn = seq_lds[1];

    #pragma unroll 2
    for (int t = 0; t < LSEQ - 1; ++t) {
        // prefetch next step's k/v (address from token read last iteration)
        f16v  KN = *(const f16v*)&kn_lds[tokn * HH + j0];
        float vn = v_lds[tokn * HH + i];
        int tokn2 = seq_lds[t + 2];   // padded, safe at t = LSEQ-2

        // vp_i partial over this thread's 16 columns (4 independent chains)
        float p0 = 0.f, p1 = 0.f, p2 = 0.f, p3 = 0.f;
        #pragma unroll
        for (int jj = 0; jj < 4; ++jj) {
            p0 = fmaf(M[jj],      K[jj],      p0);
            p1 = fmaf(M[4 + jj],  K[4 + jj],  p1);
            p2 = fmaf(M[8 + jj],  K[8 + jj],  p2);
            p3 = fmaf(M[12 + jj], K[12 + jj], p3);
        }
        float p = (p0 + p1) + (p2 + p3);
        p += __shfl_xor(p, 1);
        p += __shfl_xor(p, 2);
        float d = vi - p;

        // rank-1 update of this thread's slice
        #pragma unroll
        for (int jj = 0; jj < 16; ++jj) M[jj] = fmaf(d, K[jj], M[jj]);

        K = KN; vi = vn; tokn = tokn2;
    }

    // r_i = sum_j M[i][j] * q_j  with q = q_table[last token]
    {
        const int qtok = seq_lds[LSEQ - 1];
        const float* qrow = q_t + qtok * HH + j0;
        float p0 = 0.f, p1 = 0.f;
        #pragma unroll
        for (int jj = 0; jj < 8; ++jj) {
            p0 = fmaf(M[jj],     qrow[jj],     p0);
            p1 = fmaf(M[8 + jj], qrow[8 + jj], p1);
        }
        float p = p0 + p1;
        p += __shfl_xor(p, 1);
        p += __shfl_xor(p, 2);
        if ((tid & 3) == 0) r_lds[i] = p;
    }
    __syncthreads();

    // t = r @ wrp + brp
    if (tid < HH) {
        float s = brp[tid];
        #pragma unroll 8
        for (int ii = 0; ii < HH; ++ii) s = fmaf(r_lds[ii], wrp[ii * HH + tid], s);
        t_lds[tid] = s;
    }
    __syncthreads();

    // out = t @ wout + bout
    if (tid < HH) {
        float s = bout[tid];
        #pragma unroll 8
        for (int h = 0; h < HH; ++h) s = fmaf(t_lds[h], wout[h * VOC + tid], s);
        out[(long)b * VOC + tid] = s;
    }
}

extern "C" void kernel_launch(void* const* d_in, const int* in_sizes, int n_in,
                              void* d_out, int out_size, void* d_ws, size_t ws_size,
                              hipStream_t stream)
{
    const int*   seq   = (const int*)  d_in[0];
    const float* embed = (const float*)d_in[1];
    const float* w1    = (const float*)d_in[2];
    const float* b1    = (const float*)d_in[3];
    const float* w2    = (const float*)d_in[4];
    const float* b2    = (const float*)d_in[5];
    const float* ln_g  = (const float*)d_in[6];
    const float* ln_b  = (const float*)d_in[7];
    const float* wk    = (const float*)d_in[8];
    const float* wv    = (const float*)d_in[9];
    const float* wq    = (const float*)d_in[10];
    const float* wrp   = (const float*)d_in[11];
    const float* brp   = (const float*)d_in[12];
    const float* wout  = (const float*)d_in[13];
    const float* bout  = (const float*)d_in[14];
    float* out = (float*)d_out;

    float* kn_t = (float*)d_ws;
    float* v_t  = kn_t + VOC * HH;
    float* q_t  = v_t  + VOC * HH;

    const int B = in_sizes[0] / LSEQ;   // 256

    hipLaunchKernelGGL(build_tables, dim3(VOC), dim3(H2), 0, stream,
                       embed, w1, b1, w2, b2, ln_g, ln_b, wk, wv, wq,
                       kn_t, v_t, q_t);
    hipLaunchKernelGGL(delta_scan, dim3(B), dim3(256), 0, stream,
                       seq, kn_t, v_t, q_t, wrp, brp, wout, bout, out);
}

// Round 3
// 275.796 us; speedup vs baseline: 1.8278x; 1.8278x over previous
//
#include <hip/hip_runtime.h>
#include <hip/hip_bf16.h>

#define HH   64
#define H2   128
#define VOC  64
#define LSEQ 2048

typedef float f2 __attribute__((ext_vector_type(2)));

// ---------------------------------------------------------------------------
// Kernel 1: collapse embed -> FFN -> LN -> {kn, v, q} projections into
// per-token tables (VOCAB=64 entries of H=64 floats each).  (unchanged)
// ---------------------------------------------------------------------------
__global__ __launch_bounds__(128) void build_tables(
    const float* __restrict__ embed, const float* __restrict__ w1, const float* __restrict__ b1,
    const float* __restrict__ w2, const float* __restrict__ b2,
    const float* __restrict__ ln_g, const float* __restrict__ ln_b,
    const float* __restrict__ wk, const float* __restrict__ wv, const float* __restrict__ wq,
    float* __restrict__ kn_t, float* __restrict__ v_t, float* __restrict__ q_t)
{
    const int tok = blockIdx.x;
    const int tid = threadIdx.x;
    __shared__ float e_lds[HH];
    __shared__ float h_lds[H2];
    __shared__ float hs_lds[HH];

    if (tid < HH) e_lds[tid] = embed[tok * HH + tid];
    __syncthreads();

    {
        float s = b1[tid];
        #pragma unroll 8
        for (int i = 0; i < HH; ++i) s = fmaf(e_lds[i], w1[i * H2 + tid], s);
        h_lds[tid] = fmaxf(s, 0.f);
    }
    __syncthreads();

    if (tid < HH) {
        float f = b2[tid];
        #pragma unroll 8
        for (int j = 0; j < H2; ++j) f = fmaf(h_lds[j], w2[j * HH + tid], f);
        float x = e_lds[tid] + f;
        float sum = x, sq = x * x;
        #pragma unroll
        for (int m = 1; m < 64; m <<= 1) { sum += __shfl_xor(sum, m); sq += __shfl_xor(sq, m); }
        float mu  = sum * (1.f / HH);
        float var = sq * (1.f / HH) - mu * mu;
        hs_lds[tid] = (x - mu) * rsqrtf(var + 1e-5f) * ln_g[tid] + ln_b[tid];
    }
    __syncthreads();

    if (tid < HH) {
        float k = 0.f, v = 0.f, q = 0.f;
        #pragma unroll 8
        for (int j = 0; j < HH; ++j) {
            float h = hs_lds[j];
            k = fmaf(h, wk[j * HH + tid], k);
            v = fmaf(h, wv[j * HH + tid], v);
            q = fmaf(h, wq[j * HH + tid], q);
        }
        float kk = k * k;
        #pragma unroll
        for (int m = 1; m < 64; m <<= 1) kk += __shfl_xor(kk, m);
        float kn = k / fmaxf(sqrtf(kk), 1e-12f);
        kn_t[tok * HH + tid] = kn;
        v_t [tok * HH + tid] = v;
        q_t [tok * HH + tid] = q;
    }
}

// ---------------------------------------------------------------------------
// Kernel 2: per-batch sequential delta-rule scan + fused output head.
// Thread (i = tid>>2, jg = tid&3) owns M[i][jg*16 .. +15] as 8 float2 regs.
// Critical-path fix vs v1: the quad reduce is v_mov_b32 DPP quad_perm
// (VALU latency) instead of __shfl_xor (ds_bpermute, ~120cy LDS latency).
// All FMA work expressed as float2 to get v_pk_fma_f32 (2x issue rate).
// Explicit 2-deep register double-buffer (KA/KB) — no K=KN vector copy.
// ---------------------------------------------------------------------------
__device__ __forceinline__ float quad_sum(float p) {
    // + lane^1 : quad_perm [1,0,3,2] = 0xB1 ; + lane^2 : quad_perm [2,3,0,1] = 0x4E
    int q = __builtin_amdgcn_mov_dpp(__builtin_bit_cast(int, p), 0xB1, 0xF, 0xF, true);
    p += __builtin_bit_cast(float, q);
    q = __builtin_amdgcn_mov_dpp(__builtin_bit_cast(int, p), 0x4E, 0xF, 0xF, true);
    p += __builtin_bit_cast(float, q);
    return p;
}

__device__ __forceinline__ void loadK(f2 K[8], const float* __restrict__ src) {
    const float4* p = (const float4*)src;
    float4 x = p[0], y = p[1], z = p[2], w = p[3];
    K[0] = (f2){x.x, x.y}; K[1] = (f2){x.z, x.w};
    K[2] = (f2){y.x, y.y}; K[3] = (f2){y.z, y.w};
    K[4] = (f2){z.x, z.y}; K[5] = (f2){z.z, z.w};
    K[6] = (f2){w.x, w.y}; K[7] = (f2){w.z, w.w};
}

__device__ __forceinline__ void stepM(f2 M2[8], const f2 K[8], float vi) {
    f2 c0 = M2[0] * K[0] + M2[4] * K[4];
    f2 c1 = M2[1] * K[1] + M2[5] * K[5];
    f2 c2 = M2[2] * K[2] + M2[6] * K[6];
    f2 c3 = M2[3] * K[3] + M2[7] * K[7];
    f2 c  = (c0 + c1) + (c2 + c3);
    float p = c[0] + c[1];
    p = quad_sum(p);
    float d = vi - p;
    f2 d2 = {d, d};
    #pragma unroll
    for (int n = 0; n < 8; ++n) M2[n] += d2 * K[n];
}

__global__ __launch_bounds__(256) void delta_scan(
    const int* __restrict__ seq,
    const float* __restrict__ kn_t, const float* __restrict__ v_t, const float* __restrict__ q_t,
    const float* __restrict__ wrp, const float* __restrict__ brp,
    const float* __restrict__ wout, const float* __restrict__ bout,
    float* __restrict__ out)
{
    __shared__ __align__(64) float kn_lds[VOC * HH];
    __shared__ __align__(64) float v_lds[VOC * HH];
    __shared__ __align__(16) int   seq_lds[LSEQ + 4];
    __shared__ float r_lds[HH];
    __shared__ float t_lds[HH];

    const int b   = blockIdx.x;
    const int tid = threadIdx.x;

    // cooperative staging: tables (2 x 16KB) + token row (8KB)
    {
        const float4* s1 = (const float4*)kn_t; float4* d1 = (float4*)kn_lds;
        const float4* s2 = (const float4*)v_t;  float4* d2 = (float4*)v_lds;
        #pragma unroll
        for (int r = 0; r < 4; ++r) {
            d1[tid + 256 * r] = s1[tid + 256 * r];
            d2[tid + 256 * r] = s2[tid + 256 * r];
        }
        const int4* s3 = (const int4*)(seq + (long)b * LSEQ);
        int4* d3 = (int4*)seq_lds;
        #pragma unroll
        for (int r = 0; r < 2; ++r) d3[tid + 256 * r] = s3[tid + 256 * r];
    }
    __syncthreads();

    const int i  = tid >> 2;          // M row this thread contributes to
    const int j0 = (tid & 3) * 16;    // column slice base

    f2 M2[8];
    #pragma unroll
    for (int n = 0; n < 8; ++n) M2[n] = (f2){0.f, 0.f};

    f2 KA[8], KB[8];
    float vA, vB;
    int tA = seq_lds[0];
    int tB = seq_lds[1];
    loadK(KA, &kn_lds[tA * HH + j0]);
    vA = v_lds[tA * HH + i];

    // steps 0..2045 in pairs; step 2046 in the tail. Max seq_lds index read:
    // t+3 at t=2044 -> 2047 (in bounds).
    for (int t = 0; t < LSEQ - 3; t += 2) {
        loadK(KB, &kn_lds[tB * HH + j0]);      // K for step t+1
        vB = v_lds[tB * HH + i];
        int tC = seq_lds[t + 2];
        stepM(M2, KA, vA);                     // step t
        loadK(KA, &kn_lds[tC * HH + j0]);      // K for step t+2
        vA = v_lds[tC * HH + i];
        tB = seq_lds[t + 3];
        stepM(M2, KB, vB);                     // step t+1
    }
    stepM(M2, KA, vA);                         // step 2046

    // r_i = sum_j M[i][j] * q_j  with q = q_table[last token]
    {
        const int qtok = seq_lds[LSEQ - 1];
        const float* qrow = q_t + (long)qtok * HH + j0;
        f2 a0 = (f2){0.f, 0.f}, a1 = (f2){0.f, 0.f};
        #pragma unroll
        for (int n = 0; n < 4; ++n) {
            f2 q0 = (f2){qrow[2*n],     qrow[2*n + 1]};
            f2 q1 = (f2){qrow[2*n + 8], qrow[2*n + 9]};
            a0 += M2[n]     * q0;
            a1 += M2[n + 4] * q1;
        }
        f2 a = a0 + a1;
        float p = a[0] + a[1];
        p = quad_sum(p);
        if ((tid & 3) == 0) r_lds[i] = p;
    }
    __syncthreads();

    // t = r @ wrp + brp
    if (tid < HH) {
        float s = brp[tid];
        #pragma unroll 8
        for (int ii = 0; ii < HH; ++ii) s = fmaf(r_lds[ii], wrp[ii * HH + tid], s);
        t_lds[tid] = s;
    }
    __syncthreads();

    // out = t @ wout + bout
    if (tid < HH) {
        float s = bout[tid];
        #pragma unroll 8
        for (int h = 0; h < HH; ++h) s = fmaf(t_lds[h], wout[h * VOC + tid], s);
        out[(long)b * VOC + tid] = s;
    }
}

extern "C" void kernel_launch(void* const* d_in, const int* in_sizes, int n_in,
                              void* d_out, int out_size, void* d_ws, size_t ws_size,
                              hipStream_t stream)
{
    const int*   seq   = (const int*)  d_in[0];
    const float* embed = (const float*)d_in[1];
    const float* w1    = (const float*)d_in[2];
    const float* b1    = (const float*)d_in[3];
    const float* w2    = (const float*)d_in[4];
    const float* b2    = (const float*)d_in[5];
    const float* ln_g  = (const float*)d_in[6];
    const float* ln_b  = (const float*)d_in[7];
    const float* wk    = (const float*)d_in[8];
    const float* wv    = (const float*)d_in[9];
    const float* wq    = (const float*)d_in[10];
    const float* wrp   = (const float*)d_in[11];
    const float* brp   = (const float*)d_in[12];
    const float* wout  = (const float*)d_in[13];
    const float* bout  = (const float*)d_in[14];
    float* out = (float*)d_out;

    float* kn_t = (float*)d_ws;
    float* v_t  = kn_t + VOC * HH;
    float* q_t  = v_t  + VOC * HH;

    const int B = in_sizes[0] / LSEQ;   // 256

    hipLaunchKernelGGL(build_tables, dim3(VOC), dim3(H2), 0, stream,
                       embed, w1, b1, w2, b2, ln_g, ln_b, wk, wv, wq,
                       kn_t, v_t, q_t);
    hipLaunchKernelGGL(delta_scan, dim3(B), dim3(256), 0, stream,
                       seq, kn_t, v_t, q_t, wrp, brp, wout, bout, out);
}